// Round 1
// baseline (232.935 us; speedup 1.0000x reference)
//
#include <hip/hip_runtime.h>

// BayesTensorRing: out[i] = trace( M0'·M1'·M2'·M3' ), Md' = core_d[idx_d] * diag(lam_d)
// ranks all 16, dims all 200, N = 500000 samples.
//
// Layout: 4 lanes per sample (lane j owns rows 4j..4j+3 of the running product).
// 256-thread block = 64 samples. M1'/M2' staged per-sample in LDS (padded slots).

constexpr int SPB  = 64;     // samples per block
constexpr int BLK  = 256;    // threads per block
constexpr int MROW = 260;    // floats per LDS slot: 256 data + 4 pad (bank spread, keeps 16B align)

#define DEV static __device__ __forceinline__

// b[r][k] = sum_n a[r][n] * m[n*16+k]   (m = one staged 16x16 slice in LDS)
DEV void mm16(const float (&a)[4][16], float (&b)[4][16], const float* __restrict__ m)
{
#pragma unroll
    for (int nn = 0; nn < 16; ++nn) {
        float mrow[16];
#pragma unroll
        for (int q = 0; q < 4; ++q) {
            const float4 v = *reinterpret_cast<const float4*>(m + 16 * nn + 4 * q);
            mrow[4 * q + 0] = v.x; mrow[4 * q + 1] = v.y;
            mrow[4 * q + 2] = v.z; mrow[4 * q + 3] = v.w;
        }
#pragma unroll
        for (int r = 0; r < 4; ++r) {
            const float av = a[r][nn];
            if (nn == 0) {
#pragma unroll
                for (int k = 0; k < 16; ++k) b[r][k] = av * mrow[k];
            } else {
#pragma unroll
                for (int k = 0; k < 16; ++k) b[r][k] = fmaf(av, mrow[k], b[r][k]);
            }
        }
    }
}

// Lane j stages rows 4j..4j+3 of core[index] (scaled by lam over columns) into dst slot.
DEV void stage_slice(const float* __restrict__ core, const float* __restrict__ lam,
                     int index, int j, float* dst)
{
    const float4* src = reinterpret_cast<const float4*>(core + 256l * index) + 16 * j;
    float4 lv[4];
#pragma unroll
    for (int q = 0; q < 4; ++q) lv[q] = reinterpret_cast<const float4*>(lam)[q];
#pragma unroll
    for (int t = 0; t < 16; ++t) {
        float4 v = src[t];
        const float4 L = lv[t & 3];
        v.x *= L.x; v.y *= L.y; v.z *= L.z; v.w *= L.w;
        *reinterpret_cast<float4*>(dst + 64 * j + 4 * t) = v;
    }
}

__global__ __launch_bounds__(BLK, 2)
void tr_trace_kernel(const int* __restrict__ idx,
                     const float* __restrict__ c0, const float* __restrict__ l0,
                     const float* __restrict__ c1, const float* __restrict__ l1,
                     const float* __restrict__ c2, const float* __restrict__ l2,
                     const float* __restrict__ c3, const float* __restrict__ l3,
                     float* __restrict__ out, int n)
{
    __shared__ __align__(16) float mbuf[SPB * MROW];   // 66,560 B -> 2 blocks/CU

    const int tid  = threadIdx.x;
    const int slot = tid >> 2;          // sample slot in block, 0..63
    const int j    = tid & 3;           // lane within sample group
    const int s    = blockIdx.x * SPB + slot;
    const bool valid = s < n;
    const int sc   = valid ? s : n - 1; // clamp so control flow stays uniform

    const int4 ix = *reinterpret_cast<const int4*>(idx + 4l * sc);

    float* myb = mbuf + slot * MROW;

    // ---- stage M1' into LDS (each group writes only its own slot; barriers for safety)
    stage_slice(c1, l1, ix.y, j, myb);

    // ---- acc = M0' rows 4j..4j+3 (cols scaled by lam0), straight from global/L2
    float a[4][16];
    {
        const float4* src = reinterpret_cast<const float4*>(c0 + 256l * ix.x) + 16 * j;
        float4 lv[4];
#pragma unroll
        for (int q = 0; q < 4; ++q) lv[q] = reinterpret_cast<const float4*>(l0)[q];
#pragma unroll
        for (int t = 0; t < 16; ++t) {
            const float4 v = src[t];
            const float4 L = lv[t & 3];
            const int r = t >> 2, c = (t & 3) * 4;
            a[r][c + 0] = v.x * L.x; a[r][c + 1] = v.y * L.y;
            a[r][c + 2] = v.z * L.z; a[r][c + 3] = v.w * L.w;
        }
    }

    __syncthreads();

    // ---- b = a @ M1'
    float b[4][16];
    mm16(a, b, myb);

    __syncthreads();

    // ---- stage M2' (recycle the slot)
    stage_slice(c2, l2, ix.z, j, myb);

    __syncthreads();

    // ---- a = b @ M2'
    mm16(b, a, myb);

    // ---- trace with M3': partial_r = sum_n a[r][n] * c3[i3][n][4j+r], then * lam3[4j+r]
    float4 part = make_float4(0.f, 0.f, 0.f, 0.f);
    const float* base3 = c3 + 256l * ix.w + 4 * j;
#pragma unroll
    for (int nn = 0; nn < 16; ++nn) {
        const float4 v = *reinterpret_cast<const float4*>(base3 + 16 * nn);
        part.x = fmaf(a[0][nn], v.x, part.x);
        part.y = fmaf(a[1][nn], v.y, part.y);
        part.z = fmaf(a[2][nn], v.z, part.z);
        part.w = fmaf(a[3][nn], v.w, part.w);
    }
    const float4 L3 = reinterpret_cast<const float4*>(l3)[j];
    float p = part.x * L3.x + part.y * L3.y + part.z * L3.z + part.w * L3.w;

    // group reduce across 4 lanes (xor 1, xor 2 stay inside the group)
    p += __shfl_xor(p, 1);
    p += __shfl_xor(p, 2);

    if (valid && j == 0) out[s] = p;
}

extern "C" void kernel_launch(void* const* d_in, const int* in_sizes, int n_in,
                              void* d_out, int out_size, void* d_ws, size_t ws_size,
                              hipStream_t stream)
{
    const int*   idx = (const int*)  d_in[0];
    const float* c0  = (const float*)d_in[1];
    const float* l0  = (const float*)d_in[2];
    const float* c1  = (const float*)d_in[3];
    const float* l1  = (const float*)d_in[4];
    const float* c2  = (const float*)d_in[5];
    const float* l2  = (const float*)d_in[6];
    const float* c3  = (const float*)d_in[7];
    const float* l3  = (const float*)d_in[8];
    float* out = (float*)d_out;

    const int n    = out_size;                 // 500000
    const int grid = (n + SPB - 1) / SPB;      // 7813 blocks

    hipLaunchKernelGGL(tr_trace_kernel, dim3(grid), dim3(BLK), 0, stream,
                       idx, c0, l0, c1, l1, c2, l2, c3, l3, out, n);
}

// Round 2
// 155.134 us; speedup vs baseline: 1.5015x; 1.5015x over previous
//
#include <hip/hip_runtime.h>

// BayesTensorRing: out[i] = trace( M0'·M1'·M2'·M3' ), Md' = core_d[idx_d] * diag(lam_d)
// ranks 16, dims 200, N = 500000.
//
// 4 lanes/sample (lane j owns rows 4j..4j+3 of the running 16x16 product).
// 256-thread block = 64 samples. M1'/M2' staged per-sample in a private LDS slot.
// Groups never straddle a wave and never touch another group's slot -> NO block
// barriers; per-wave s_waitcnt lgkmcnt(0) provides the LDS write->read ordering.
// Lambda is folded into the cores by a tiny precompute kernel into d_ws.

constexpr int SPB  = 64;     // samples per block
constexpr int BLK  = 256;    // threads per block
constexpr int MROW = 260;    // floats per LDS slot: 256 data + 4 pad (inter-slot bank spread)

#define DEV static __device__ __forceinline__

// b[r][k] = sum_n a[r][n] * m[n*16+k]   (m = staged 16x16 slice, row-major, in LDS)
// Reads are 4-lane same-address broadcasts (conflict-free).
DEV void mm16(const float (&a)[4][16], float (&b)[4][16], const float* __restrict__ m)
{
#pragma unroll
    for (int nn = 0; nn < 16; ++nn) {
        float mrow[16];
#pragma unroll
        for (int q = 0; q < 4; ++q) {
            const float4 v = *reinterpret_cast<const float4*>(m + 16 * nn + 4 * q);
            mrow[4 * q + 0] = v.x; mrow[4 * q + 1] = v.y;
            mrow[4 * q + 2] = v.z; mrow[4 * q + 3] = v.w;
        }
#pragma unroll
        for (int r = 0; r < 4; ++r) {
            const float av = a[r][nn];
            if (nn == 0) {
#pragma unroll
                for (int k = 0; k < 16; ++k) b[r][k] = av * mrow[k];
            } else {
#pragma unroll
                for (int k = 0; k < 16; ++k) b[r][k] = fmaf(av, mrow[k], b[r][k]);
            }
        }
    }
}

// Lane j stages float4s #(4t+j), t=0..15: global read is 64B-contiguous per group,
// LDS write is 4 consecutive float4s per group (conflict-free). Column block of
// float4 #(4t+j) is 4j -> lambda factor is a single float4 per lane.
template<bool SCALED>
DEV void stage_slice(const float* __restrict__ core, const float* __restrict__ lam,
                     int index, int j, float* __restrict__ dst)
{
    const float4* src = reinterpret_cast<const float4*>(core + 256l * index);
    float4* d4 = reinterpret_cast<float4*>(dst);
    float4 L;
    if constexpr (!SCALED) L = reinterpret_cast<const float4*>(lam)[j];
#pragma unroll
    for (int t = 0; t < 16; ++t) {
        float4 v = src[4 * t + j];
        if constexpr (!SCALED) { v.x *= L.x; v.y *= L.y; v.z *= L.z; v.w *= L.w; }
        d4[4 * t + j] = v;
    }
}

template<bool SCALED>
__global__ __launch_bounds__(BLK, 2)
void tr_trace_kernel(const int* __restrict__ idx,
                     const float* __restrict__ c0, const float* __restrict__ l0,
                     const float* __restrict__ c1, const float* __restrict__ l1,
                     const float* __restrict__ c2, const float* __restrict__ l2,
                     const float* __restrict__ c3, const float* __restrict__ l3,
                     float* __restrict__ out, int n)
{
    __shared__ __align__(16) float mbuf[SPB * MROW];   // 66,560 B -> 2 blocks/CU

    const int tid  = threadIdx.x;
    const int slot = tid >> 2;          // sample slot in block, 0..63
    const int j    = tid & 3;           // lane within 4-lane sample group
    const int s    = blockIdx.x * SPB + slot;
    const int sc   = s < n ? s : n - 1; // clamp (keeps loads in-bounds)

    const int4 ix = *reinterpret_cast<const int4*>(idx + 4l * sc);
    float* myb = mbuf + slot * MROW;

    // ---- stage M1' into this group's LDS slot
    stage_slice<SCALED>(c1, l1, ix.y, j, myb);

    // ---- acc = M0' rows 4j..4j+3, straight from global (L2-resident)
    float a[4][16], b[4][16];
    {
        const float4* src = reinterpret_cast<const float4*>(c0 + 256l * ix.x) + 16 * j;
        float4 lv[4];
        if constexpr (!SCALED) {
#pragma unroll
            for (int q = 0; q < 4; ++q) lv[q] = reinterpret_cast<const float4*>(l0)[q];
        }
#pragma unroll
        for (int t = 0; t < 16; ++t) {
            float4 v = src[t];
            if constexpr (!SCALED) {
                const float4 L = lv[t & 3];
                v.x *= L.x; v.y *= L.y; v.z *= L.z; v.w *= L.w;
            }
            const int r = t >> 2, c = (t & 3) * 4;
            a[r][c + 0] = v.x; a[r][c + 1] = v.y;
            a[r][c + 2] = v.z; a[r][c + 3] = v.w;
        }
    }

    // wave-local ordering: M1' writes visible before broadcast reads
    asm volatile("s_waitcnt lgkmcnt(0)" ::: "memory");

    // ---- b = a @ M1'
    mm16(a, b, myb);

    // all M1' reads returned before the slot is overwritten (WAR)
    asm volatile("s_waitcnt lgkmcnt(0)" ::: "memory");

    // ---- stage M2' (recycle the slot)
    stage_slice<SCALED>(c2, l2, ix.z, j, myb);

    asm volatile("s_waitcnt lgkmcnt(0)" ::: "memory");

    // ---- a = b @ M2'
    mm16(b, a, myb);

    // ---- trace with M3': part.r = sum_n a[r][n] * c3'[i3][n][4j+r]
    float4 part = make_float4(0.f, 0.f, 0.f, 0.f);
    const float* base3 = c3 + 256l * ix.w + 4 * j;
#pragma unroll
    for (int nn = 0; nn < 16; ++nn) {
        const float4 v = *reinterpret_cast<const float4*>(base3 + 16 * nn);
        part.x = fmaf(a[0][nn], v.x, part.x);
        part.y = fmaf(a[1][nn], v.y, part.y);
        part.z = fmaf(a[2][nn], v.z, part.z);
        part.w = fmaf(a[3][nn], v.w, part.w);
    }
    float p;
    if constexpr (!SCALED) {
        const float4 L3 = reinterpret_cast<const float4*>(l3)[j];
        p = part.x * L3.x + part.y * L3.y + part.z * L3.z + part.w * L3.w;
    } else {
        p = part.x + part.y + part.z + part.w;
    }

    // reduce across the 4-lane group
    p += __shfl_xor(p, 1);
    p += __shfl_xor(p, 2);

    if (s < n && j == 0) out[s] = p;
}

// ws[d][i][r][c] = core_d[i][r][c] * lam_d[c]; 4 x 200 x 16 x 16 floats = 819,200 B.
__global__ __launch_bounds__(256)
void scale_cores_kernel(const float* __restrict__ c0, const float* __restrict__ l0,
                        const float* __restrict__ c1, const float* __restrict__ l1,
                        const float* __restrict__ c2, const float* __restrict__ l2,
                        const float* __restrict__ c3, const float* __restrict__ l3,
                        float* __restrict__ ws)
{
    const int gid = blockIdx.x * 256 + threadIdx.x;   // float4 id, 0..51199
    const int d   = gid / 12800;                      // uniform per block (12800 % 256 == 0)
    const int w   = gid - d * 12800;
    const float* cs[4] = {c0, c1, c2, c3};
    const float* ls[4] = {l0, l1, l2, l3};
    const float4 v = reinterpret_cast<const float4*>(cs[d])[w];
    const float4 L = reinterpret_cast<const float4*>(ls[d])[w & 3];
    float4 o;
    o.x = v.x * L.x; o.y = v.y * L.y; o.z = v.z * L.z; o.w = v.w * L.w;
    reinterpret_cast<float4*>(ws)[d * 12800 + w] = o;
}

extern "C" void kernel_launch(void* const* d_in, const int* in_sizes, int n_in,
                              void* d_out, int out_size, void* d_ws, size_t ws_size,
                              hipStream_t stream)
{
    const int*   idx = (const int*)  d_in[0];
    const float* c0  = (const float*)d_in[1];
    const float* l0  = (const float*)d_in[2];
    const float* c1  = (const float*)d_in[3];
    const float* l1  = (const float*)d_in[4];
    const float* c2  = (const float*)d_in[5];
    const float* l2  = (const float*)d_in[6];
    const float* c3  = (const float*)d_in[7];
    const float* l3  = (const float*)d_in[8];
    float* out = (float*)d_out;

    const int n    = out_size;                 // 500000
    const int grid = (n + SPB - 1) / SPB;      // 7813 blocks

    const size_t need = 4ull * 200 * 256 * sizeof(float);  // 819,200 B
    if (ws_size >= need) {
        float* w = (float*)d_ws;
        hipLaunchKernelGGL(scale_cores_kernel, dim3(200), dim3(256), 0, stream,
                           c0, l0, c1, l1, c2, l2, c3, l3, w);
        hipLaunchKernelGGL((tr_trace_kernel<true>), dim3(grid), dim3(BLK), 0, stream,
                           idx, w, nullptr, w + 51200, nullptr,
                           w + 102400, nullptr, w + 153600, nullptr, out, n);
    } else {
        hipLaunchKernelGGL((tr_trace_kernel<false>), dim3(grid), dim3(BLK), 0, stream,
                           idx, c0, l0, c1, l1, c2, l2, c3, l3, out, n);
    }
}